// Round 5
// baseline (2978.978 us; speedup 1.0000x reference)
//
#include <hip/hip_runtime.h>

#define HD 50
#define NG 200
#define TT 512
#define BRR 16         // batch rows per block -> 256 blocks = 1/CU
#define PS 212         // pre row stride (floats): 2-way scatter conflicts, 8B-aligned
#define HS 72          // h row stride (shorts) = 144 B

using bf16x8 = __attribute__((ext_vector_type(8))) short;
using f32x4  = __attribute__((ext_vector_type(4))) float;
using f32x2  = __attribute__((ext_vector_type(2))) float;

__device__ __forceinline__ unsigned short f2bf(float f) {   // RNE float->bf16
    unsigned int u = __float_as_uint(f);
    u += 0x7FFFu + ((u >> 16) & 1u);
    return (unsigned short)(u >> 16);
}
__device__ __forceinline__ float bf2f(unsigned short b) {
    return __uint_as_float(((unsigned int)b) << 16);
}
__device__ __forceinline__ float frcp(float x) { return __builtin_amdgcn_rcpf(x); }
__device__ __forceinline__ float sigf(float x) { return frcp(1.0f + __expf(-x)); }
__device__ __forceinline__ float tanhfast(float x) {
    return 1.0f - 2.0f * frcp(__expf(2.0f * x) + 1.0f);
}

// Waves 0-3: all 13 L0 tiles (step n). Waves 4-7: all 13 L1 tiles (step n-1).
// Weights as bf16 hi/lo B-fragments, register-resident. 3-term split product.
// EW spread over 400 threads (2 adjacent units each, both layers); wave-7
// threads 448-495 prefetch x(n+1) from global and write it into the A buffer.
__global__ __launch_bounds__(512, 2) void lstm2_mfma2(
    const float* __restrict__ x,
    const float* __restrict__ Wih0, const float* __restrict__ Whh0,
    const float* __restrict__ bih0, const float* __restrict__ bhh0,
    const float* __restrict__ Wih1, const float* __restrict__ Whh1,
    const float* __restrict__ bih1, const float* __restrict__ bhh1,
    const float* __restrict__ Wfc, const float* __restrict__ bfc,
    float* __restrict__ out)
{
    __shared__ float s_pre0[BRR][PS];
    __shared__ float s_pre1[BRR][PS];
    __shared__ short s_h0hi[2][BRR][HS], s_h0lo[2][BRR][HS];  // k: 0-49 h0, 50-52 x, 53+ zero
    __shared__ short s_h1hi[2][BRR][HS], s_h1lo[2][BRR][HS];  // k: 0-49 h1, 50+ zero

    const int tid  = threadIdx.x;
    const int wid  = tid >> 6;
    const int lane = tid & 63;
    const int lr   = lane & 15;    // A/D row or B/D col
    const int lq   = lane >> 4;    // k-octet / D row-quad
    const int r0   = blockIdx.x * BRR;
    const bool pathA = (wid < 4);

    // tile tables: L0 w0-3 {0,4,7,10}/{4,3,3,3}; L1 w4-7 {0,3,6,10}/{3,3,4,3}
    const int l0b[4] = {0,4,7,10}, l0c[4] = {4,3,3,3};
    const int l1b[4] = {0,3,6,10}, l1c[4] = {3,3,4,3};
    const int tbase = pathA ? l0b[wid] : l1b[wid-4];
    const int tcnt  = pathA ? l0c[wid] : l1c[wid-4];

    // ---- weight B-fragments (hi/lo), register-resident ----
    bf16x8 bh[4][4], bl[4][4];
    int gT[4]; int slT[4]; float bvT[4];
    #pragma unroll
    for (int tt = 0; tt < 4; ++tt) {
        #pragma unroll
        for (int s = 0; s < 4; ++s) { bh[tt][s] = (bf16x8)0; bl[tt][s] = (bf16x8)0; }
        const int g = (tbase + tt)*16 + lr;
        gT[tt] = g;
        const bool v = (tt < tcnt) && (g < NG);
        slT[tt] = v ? (g/HD)*52 + (g%HD) : 0;
        if (pathA) {
            bvT[tt] = v ? bih0[g] + bhh0[g] : 0.f;
            #pragma unroll
            for (int s = 0; s < 2; ++s) {
                #pragma unroll
                for (int j = 0; j < 8; ++j) {
                    const int k = s*32 + lq*8 + j;
                    float wv = 0.f;
                    if (v) {
                        if (k < HD) wv = Whh0[g*HD + k];
                        else if (k < HD+3) wv = Wih0[g*3 + (k-HD)];
                    }
                    const unsigned short hb = f2bf(wv);
                    bh[tt][s][j] = (short)hb;
                    bl[tt][s][j] = (short)f2bf(wv - bf2f(hb));
                }
            }
        } else {
            bvT[tt] = v ? bih1[g] + bhh1[g] : 0.f;
            #pragma unroll
            for (int s = 0; s < 4; ++s) {
                #pragma unroll
                for (int j = 0; j < 8; ++j) {
                    const int k = s*32 + lq*8 + j;   // 0-63: Wih1 k-space, 64-127: Whh1
                    float wv = 0.f;
                    if (v) {
                        if (k < HD) wv = Wih1[g*HD + k];
                        else if (k >= 64 && k < 64+HD) wv = Whh1[g*HD + (k-64)];
                    }
                    const unsigned short hb = f2bf(wv);
                    bh[tt][s][j] = (short)hb;
                    bl[tt][s][j] = (short)f2bf(wv - bf2f(hb));
                }
            }
        }
    }

    // ---- EW ownership: 400 threads x (row, 2 adjacent units), both layers ----
    const bool ew = (tid < 400);
    const int  er = tid & 15;
    const int  eu = (tid >> 4) * 2;      // 0..48
    float c0a = 0.f, c0b = 0.f, c1a = 0.f, c1b = 0.f;

    // ---- x duty: threads 448-495 (wave 7) ----
    const bool xth = (tid >= 448) && (tid < 496);
    const int  xr  = (tid - 448) / 3, xd = (tid - 448) % 3;

    // ---- zero-init h buffers ----
    for (int p = tid; p < 2*BRR*HS; p += 512) {
        ((short*)s_h0hi)[p] = 0; ((short*)s_h0lo)[p] = 0;
        ((short*)s_h1hi)[p] = 0; ((short*)s_h1lo)[p] = 0;
    }
    __syncthreads();
    if (xth) {                           // x(0) -> buffer 1 (read at tick 0)
        const float xv = x[(size_t)(r0+xr)*(TT*3) + xd];
        const unsigned short xh = f2bf(xv);
        s_h0hi[1][xr][HD+xd] = (short)xh;
        s_h0lo[1][xr][HD+xd] = (short)f2bf(xv - bf2f(xh));
    }
    __syncthreads();

    // ================= main loop: 513 ticks =================
    for (int n = 0; n <= TT; ++n) {
        // x(n+1) prefetch from global (L2-resident), used in stage 2
        float xnext = 0.f;
        if (xth && (n+1) < TT)
            xnext = x[(size_t)(r0+xr)*(TT*3) + (size_t)(n+1)*3 + xd];

        // ---------- stage 1: MFMA ----------
        if (pathA) {
            if (n < TT) {                              // pre0(n) = [h0(n-1)|x(n)] @ W0
                const char* hb0 = (const char*)&s_h0hi[(n+1)&1][0][0];
                const char* lb0 = (const char*)&s_h0lo[(n+1)&1][0][0];
                bf16x8 ah[2], al[2];
                #pragma unroll
                for (int s = 0; s < 2; ++s) {
                    const int off = lr*(2*HS) + s*64 + lq*16;
                    ah[s] = *(const bf16x8*)(hb0 + off);
                    al[s] = *(const bf16x8*)(lb0 + off);
                }
                f32x4 acc[4];
                #pragma unroll
                for (int tt = 0; tt < 4; ++tt) { const float b = bvT[tt]; acc[tt] = (f32x4){b,b,b,b}; }
                #pragma unroll
                for (int s = 0; s < 2; ++s) {
                    #pragma unroll
                    for (int tt = 0; tt < 4; ++tt) if (tt < tcnt)
                        acc[tt] = __builtin_amdgcn_mfma_f32_16x16x32_bf16(ah[s], bh[tt][s], acc[tt], 0,0,0);
                    #pragma unroll
                    for (int tt = 0; tt < 4; ++tt) if (tt < tcnt)
                        acc[tt] = __builtin_amdgcn_mfma_f32_16x16x32_bf16(al[s], bh[tt][s], acc[tt], 0,0,0);
                    #pragma unroll
                    for (int tt = 0; tt < 4; ++tt) if (tt < tcnt)
                        acc[tt] = __builtin_amdgcn_mfma_f32_16x16x32_bf16(ah[s], bl[tt][s], acc[tt], 0,0,0);
                }
                #pragma unroll
                for (int tt = 0; tt < 4; ++tt) if (tt < tcnt && gT[tt] < NG) {
                    #pragma unroll
                    for (int j = 0; j < 4; ++j) s_pre0[lq*4+j][slT[tt]] = acc[tt][j];
                }
            }
        } else {
            if (n >= 1) {                              // pre1(n-1) = [h0(n-1)|h1(n-2)] @ W1
                const char* hb0 = (const char*)&s_h0hi[(n+1)&1][0][0];
                const char* lb0 = (const char*)&s_h0lo[(n+1)&1][0][0];
                const char* hb1 = (const char*)&s_h1hi[n&1][0][0];
                const char* lb1 = (const char*)&s_h1lo[n&1][0][0];
                bf16x8 ah[4], al[4];
                #pragma unroll
                for (int s = 0; s < 2; ++s) {
                    const int off = lr*(2*HS) + s*64 + lq*16;
                    ah[s]   = *(const bf16x8*)(hb0 + off);
                    al[s]   = *(const bf16x8*)(lb0 + off);
                    ah[2+s] = *(const bf16x8*)(hb1 + off);
                    al[2+s] = *(const bf16x8*)(lb1 + off);
                }
                f32x4 acc[4];
                #pragma unroll
                for (int tt = 0; tt < 4; ++tt) { const float b = bvT[tt]; acc[tt] = (f32x4){b,b,b,b}; }
                #pragma unroll
                for (int s = 0; s < 4; ++s) {
                    #pragma unroll
                    for (int tt = 0; tt < 4; ++tt) if (tt < tcnt)
                        acc[tt] = __builtin_amdgcn_mfma_f32_16x16x32_bf16(ah[s], bh[tt][s], acc[tt], 0,0,0);
                    #pragma unroll
                    for (int tt = 0; tt < 4; ++tt) if (tt < tcnt)
                        acc[tt] = __builtin_amdgcn_mfma_f32_16x16x32_bf16(al[s], bh[tt][s], acc[tt], 0,0,0);
                    #pragma unroll
                    for (int tt = 0; tt < 4; ++tt) if (tt < tcnt)
                        acc[tt] = __builtin_amdgcn_mfma_f32_16x16x32_bf16(ah[s], bl[tt][s], acc[tt], 0,0,0);
                }
                #pragma unroll
                for (int tt = 0; tt < 4; ++tt) if (tt < tcnt && gT[tt] < NG) {
                    #pragma unroll
                    for (int j = 0; j < 4; ++j) s_pre1[lq*4+j][slT[tt]] = acc[tt][j];
                }
            }
        }
        __syncthreads();

        // ---------- stage 2: elementwise ----------
        if (ew && n < TT) {                            // EW0: pre0(n) -> h0(n) in buf[n&1]
            const f32x2 pi = *(const f32x2*)&s_pre0[er][0*52 + eu];
            const f32x2 pf = *(const f32x2*)&s_pre0[er][1*52 + eu];
            const f32x2 pg = *(const f32x2*)&s_pre0[er][2*52 + eu];
            const f32x2 po = *(const f32x2*)&s_pre0[er][3*52 + eu];
            const float ca = sigf(pf[0])*c0a + sigf(pi[0])*tanhfast(pg[0]);
            const float cb = sigf(pf[1])*c0b + sigf(pi[1])*tanhfast(pg[1]);
            c0a = ca; c0b = cb;
            const float ha = sigf(po[0])*tanhfast(ca);
            const float hb = sigf(po[1])*tanhfast(cb);
            unsigned int pkh, pkl;
            asm("v_cvt_pk_bf16_f32 %0, %1, %2" : "=v"(pkh) : "v"(ha), "v"(hb));
            const float la = ha - __uint_as_float(pkh << 16);
            const float lb2 = hb - __uint_as_float(pkh & 0xffff0000u);
            asm("v_cvt_pk_bf16_f32 %0, %1, %2" : "=v"(pkl) : "v"(la), "v"(lb2));
            *(unsigned int*)&s_h0hi[n&1][er][eu] = pkh;
            *(unsigned int*)&s_h0lo[n&1][er][eu] = pkl;
        }
        if (ew && n >= 1) {                            // EW1: pre1(n-1) -> h1(n-1) in buf[(n-1)&1]
            const f32x2 pi = *(const f32x2*)&s_pre1[er][0*52 + eu];
            const f32x2 pf = *(const f32x2*)&s_pre1[er][1*52 + eu];
            const f32x2 pg = *(const f32x2*)&s_pre1[er][2*52 + eu];
            const f32x2 po = *(const f32x2*)&s_pre1[er][3*52 + eu];
            const float ca = sigf(pf[0])*c1a + sigf(pi[0])*tanhfast(pg[0]);
            const float cb = sigf(pf[1])*c1b + sigf(pi[1])*tanhfast(pg[1]);
            c1a = ca; c1b = cb;
            const float ha = sigf(po[0])*tanhfast(ca);
            const float hb = sigf(po[1])*tanhfast(cb);
            unsigned int pkh, pkl;
            asm("v_cvt_pk_bf16_f32 %0, %1, %2" : "=v"(pkh) : "v"(ha), "v"(hb));
            const float la = ha - __uint_as_float(pkh << 16);
            const float lb2 = hb - __uint_as_float(pkh & 0xffff0000u);
            asm("v_cvt_pk_bf16_f32 %0, %1, %2" : "=v"(pkl) : "v"(la), "v"(lb2));
            *(unsigned int*)&s_h1hi[(n-1)&1][er][eu] = pkh;
            *(unsigned int*)&s_h1lo[(n-1)&1][er][eu] = pkl;
        }
        if (xth && (n+1) < TT) {                       // x(n+1) -> buf[n&1] k-slots 50-52
            const unsigned short xh = f2bf(xnext);
            s_h0hi[n&1][xr][HD+xd] = (short)xh;
            s_h0lo[n&1][xr][HD+xd] = (short)f2bf(xnext - bf2f(xh));
        }
        __syncthreads();
    }

    // ---- FC epilogue: out = h1(TT-1) @ Wfc^T + bfc  (h1 final in buf 1) ----
    if (tid < BRR*7) {
        const int r = tid / 7, o = tid % 7;
        float acc = bfc[o];
        #pragma unroll
        for (int u = 0; u < HD; ++u)
            acc += (bf2f((unsigned short)s_h1hi[1][r][u]) + bf2f((unsigned short)s_h1lo[1][r][u])) * Wfc[o*HD + u];
        out[(size_t)(r0+r)*7 + o] = acc;
    }
}

extern "C" void kernel_launch(void* const* d_in, const int* in_sizes, int n_in,
                              void* d_out, int out_size, void* d_ws, size_t ws_size,
                              hipStream_t stream) {
    const float* xp    = (const float*)d_in[0];
    const float* Wih0  = (const float*)d_in[1];
    const float* Whh0  = (const float*)d_in[2];
    const float* bih0  = (const float*)d_in[3];
    const float* bhh0  = (const float*)d_in[4];
    const float* Wih1  = (const float*)d_in[5];
    const float* Whh1  = (const float*)d_in[6];
    const float* bih1  = (const float*)d_in[7];
    const float* bhh1  = (const float*)d_in[8];
    const float* Wfc   = (const float*)d_in[9];
    const float* bfc   = (const float*)d_in[10];
    float* outp = (float*)d_out;

    const int B = in_sizes[0] / (TT * 3);   // 4096
    const int grid = B / BRR;               // 256 blocks, 1 per CU

    lstm2_mfma2<<<grid, 512, 0, stream>>>(
        xp, Wih0, Whh0, bih0, bhh0, Wih1, Whh1, bih1, bhh1, Wfc, bfc, outp);
}

// Round 6
// 913.805 us; speedup vs baseline: 3.2600x; 3.2600x over previous
//
#include <hip/hip_runtime.h>
#include <math.h>

#define HD 50
#define NG 200
#define TT 512
#define BRR 16         // batch rows per block -> 256 blocks = 1/CU
#define TC 32          // x prefetch chunk (timesteps)
#define HS 72          // shorts per h row (144B stride)
#define PS 212         // pre row stride: Δ4row=848 ≡ 16 mod 32 -> 2-way (free) scatter

using bf16x8 = __attribute__((ext_vector_type(8))) short;
using f32x4  = __attribute__((ext_vector_type(4))) float;
using s4v    = __attribute__((ext_vector_type(4))) short;
using s2v    = __attribute__((ext_vector_type(2))) short;

__device__ __forceinline__ unsigned short f2bf(float f) {   // RNE float->bf16
    unsigned int u = __float_as_uint(f);
    u += 0x7FFFu + ((u >> 16) & 1u);
    return (unsigned short)(u >> 16);
}
__device__ __forceinline__ float bf2f(unsigned short b) {
    return __uint_as_float(((unsigned int)b) << 16);
}
__device__ __forceinline__ float frcp(float x) { return __builtin_amdgcn_rcpf(x); }
__device__ __forceinline__ float sigf(float x) { return frcp(1.0f + __expf(-x)); }
__device__ __forceinline__ float tanhfast(float x) {
    return 1.0f - 2.0f * frcp(__expf(2.0f * x) + 1.0f);
}

// Round-4 structure (proven 1.23 ms) + PS=212 (conflict-free pre scatter) + rcp
// activations. 8 waves: w0-3 = L0 MFMA (step n), w4-7 = L1 MFMA (step n-1).
// Weight bf16 hi/lo fragments register-resident; 3-term split product.
__global__ __launch_bounds__(512, 2) void lstm2_mfma3(
    const float* __restrict__ x,
    const float* __restrict__ Wih0, const float* __restrict__ Whh0,
    const float* __restrict__ bih0, const float* __restrict__ bhh0,
    const float* __restrict__ Wih1, const float* __restrict__ Whh1,
    const float* __restrict__ bih1, const float* __restrict__ bhh1,
    const float* __restrict__ Wfc, const float* __restrict__ bfc,
    float* __restrict__ out)
{
    __shared__ float s_pre0[BRR][PS];                 // [row][type*52+u]
    __shared__ float s_pre1[BRR][PS];
    __shared__ short s_h0hi[BRR][HS], s_h0lo[BRR][HS]; // k: 0-49 h, 50-52 x, 53-63 zero
    __shared__ short s_h1hi[BRR][HS], s_h1lo[BRR][HS];
    __shared__ float s_xs[2][BRR][TC*3];

    const int tid  = threadIdx.x;
    const int wid  = tid >> 6;
    const int lane = tid & 63;
    const int lr   = lane & 15;    // M-row (A/D) or N-col (B/D)
    const int lq   = lane >> 4;    // k-octet
    const int r0   = blockIdx.x * BRR;
    const bool pathA = (wid < 4);

    // tile assignment: L0 tiles w0:0-3 w1:4-6 w2:7-9 w3:10-12; L1 w4:0-2 w5:3-5 w6:6-8 w7:9-12
    const int tbase = pathA ? ((wid == 0) ? 0 : 1 + wid*3) : (wid - 4)*3;
    const int tcnt  = pathA ? ((wid == 0) ? 4 : 3) : ((wid == 7) ? 4 : 3);

    // ---- weight B-fragments (hi/lo), register-resident ----
    bf16x8 bh[4][4], bl[4][4];
    int   gT[4]; int slT[4]; float bvT[4];
    #pragma unroll
    for (int tt = 0; tt < 4; ++tt) {
        #pragma unroll
        for (int s = 0; s < 4; ++s) { bh[tt][s] = (bf16x8)0; bl[tt][s] = (bf16x8)0; }
        const int g = (tbase + tt)*16 + lr;
        gT[tt] = g;
        const bool v = (tt < tcnt) && (g < NG);
        slT[tt] = v ? (g/HD)*52 + (g%HD) : 0;
        if (pathA) {
            bvT[tt] = v ? bih0[g] + bhh0[g] : 0.f;
            #pragma unroll
            for (int s = 0; s < 2; ++s) {
                #pragma unroll
                for (int j = 0; j < 8; ++j) {
                    const int k = s*32 + lq*8 + j;
                    float wv = 0.f;
                    if (v) {
                        if (k < HD) wv = Whh0[g*HD + k];
                        else if (k < HD+3) wv = Wih0[g*3 + (k-HD)];
                    }
                    const unsigned short hb = f2bf(wv);
                    bh[tt][s][j] = (short)hb;
                    bl[tt][s][j] = (short)f2bf(wv - bf2f(hb));
                }
            }
        } else {
            bvT[tt] = v ? bih1[g] + bhh1[g] : 0.f;
            #pragma unroll
            for (int s = 0; s < 4; ++s) {
                #pragma unroll
                for (int j = 0; j < 8; ++j) {
                    const int k = s*32 + lq*8 + j;   // 0-63: Wih1 k-space, 64-127: Whh1
                    float wv = 0.f;
                    if (v) {
                        if (k < HD) wv = Wih1[g*HD + k];
                        else if (k >= 64 && k < 64+HD) wv = Whh1[g*HD + (k-64)];
                    }
                    const unsigned short hb = f2bf(wv);
                    bh[tt][s][j] = (short)hb;
                    bl[tt][s][j] = (short)f2bf(wv - bf2f(hb));
                }
            }
        }
    }

    // ---- elementwise ownership: 208 threads, (row, 4-unit block) ----
    const bool ew  = (tid < 208);
    const int  er  = tid / 13;
    const int  eub = (tid % 13) * 4;
    float c0r[4] = {0,0,0,0};
    float c1r[4] = {0,0,0,0};

    // ---- init LDS ----
    for (int p = tid; p < BRR*HS; p += 512) {
        const int rr = p / HS, cc = p % HS;
        s_h0hi[rr][cc] = 0; s_h0lo[rr][cc] = 0;
        s_h1hi[rr][cc] = 0; s_h1lo[rr][cc] = 0;
    }
    for (int p = tid; p < 128; p += 512) {            // zero pre pad slots (u=50,51 per type)
        const int rr = p / 8, ii = p % 8;
        s_pre0[rr][(ii>>1)*52 + 50 + (ii&1)] = 0.f;
        s_pre1[rr][(ii>>1)*52 + 50 + (ii&1)] = 0.f;
    }
    for (int p = tid; p < BRR*TC*3; p += 512) {       // stage x chunk 0
        const int rr = p / (TC*3), q = p % (TC*3);
        s_xs[0][rr][q] = x[(size_t)(r0+rr)*(TT*3) + q];
    }
    __syncthreads();
    if (tid >= 208 && tid < 256) {                    // write x(0) into A0 k-slots 50-52
        const int p = tid - 208; const int rr = p/3, d = p%3;
        const float xv = s_xs[0][rr][d];
        const unsigned short xh = f2bf(xv);
        s_h0hi[rr][HD+d] = (short)xh;
        s_h0lo[rr][HD+d] = (short)f2bf(xv - bf2f(xh));
    }
    __syncthreads();

    // ================= main loop: 513 ticks =================
    for (int n = 0; n <= TT; ++n) {
        // ---------- MFMA phase ----------
        if (pathA) {
            if (n < TT) {                              // pre0(n) = [h0(n-1)|x(n)] @ W0
                bf16x8 a0h[2], a0l[2];
                #pragma unroll
                for (int s = 0; s < 2; ++s) {
                    const int off = lr*(2*HS) + s*64 + lq*16;
                    a0h[s] = *(const bf16x8*)((const char*)&s_h0hi[0][0] + off);
                    a0l[s] = *(const bf16x8*)((const char*)&s_h0lo[0][0] + off);
                }
                f32x4 acc[4];
                #pragma unroll
                for (int tt = 0; tt < 4; ++tt) { const float b = bvT[tt]; acc[tt] = (f32x4){b,b,b,b}; }
                #pragma unroll
                for (int s = 0; s < 2; ++s) {
                    #pragma unroll
                    for (int tt = 0; tt < 4; ++tt) if (tt < tcnt)
                        acc[tt] = __builtin_amdgcn_mfma_f32_16x16x32_bf16(a0h[s], bh[tt][s], acc[tt], 0,0,0);
                    #pragma unroll
                    for (int tt = 0; tt < 4; ++tt) if (tt < tcnt)
                        acc[tt] = __builtin_amdgcn_mfma_f32_16x16x32_bf16(a0l[s], bh[tt][s], acc[tt], 0,0,0);
                    #pragma unroll
                    for (int tt = 0; tt < 4; ++tt) if (tt < tcnt)
                        acc[tt] = __builtin_amdgcn_mfma_f32_16x16x32_bf16(a0h[s], bl[tt][s], acc[tt], 0,0,0);
                }
                #pragma unroll
                for (int tt = 0; tt < 4; ++tt) if (tt < tcnt && gT[tt] < NG) {
                    #pragma unroll
                    for (int j = 0; j < 4; ++j) s_pre0[lq*4+j][slT[tt]] = acc[tt][j];
                }
            }
        } else {
            if (n >= 1) {                              // pre1(n-1) = [h0(n-1)|h1(n-2)] @ W1
                bf16x8 ah[4], al[4];
                #pragma unroll
                for (int s = 0; s < 2; ++s) {
                    const int off = lr*(2*HS) + s*64 + lq*16;
                    ah[s]   = *(const bf16x8*)((const char*)&s_h0hi[0][0] + off);
                    al[s]   = *(const bf16x8*)((const char*)&s_h0lo[0][0] + off);
                    ah[2+s] = *(const bf16x8*)((const char*)&s_h1hi[0][0] + off);
                    al[2+s] = *(const bf16x8*)((const char*)&s_h1lo[0][0] + off);
                }
                f32x4 acc[4];
                #pragma unroll
                for (int tt = 0; tt < 4; ++tt) { const float b = bvT[tt]; acc[tt] = (f32x4){b,b,b,b}; }
                #pragma unroll
                for (int s = 0; s < 4; ++s) {
                    #pragma unroll
                    for (int tt = 0; tt < 4; ++tt) if (tt < tcnt)
                        acc[tt] = __builtin_amdgcn_mfma_f32_16x16x32_bf16(ah[s], bh[tt][s], acc[tt], 0,0,0);
                    #pragma unroll
                    for (int tt = 0; tt < 4; ++tt) if (tt < tcnt)
                        acc[tt] = __builtin_amdgcn_mfma_f32_16x16x32_bf16(al[s], bh[tt][s], acc[tt], 0,0,0);
                    #pragma unroll
                    for (int tt = 0; tt < 4; ++tt) if (tt < tcnt)
                        acc[tt] = __builtin_amdgcn_mfma_f32_16x16x32_bf16(ah[s], bl[tt][s], acc[tt], 0,0,0);
                }
                #pragma unroll
                for (int tt = 0; tt < 4; ++tt) if (tt < tcnt && gT[tt] < NG) {
                    #pragma unroll
                    for (int j = 0; j < 4; ++j) s_pre1[lq*4+j][slT[tt]] = acc[tt][j];
                }
            }
        }
        __syncthreads();

        // ---------- elementwise phase ----------
        if (ew && n < TT) {                            // layer-0 EW: pre0(n) -> h0(n)
            f32x4 pi = *(const f32x4*)&s_pre0[er][0*52 + eub];
            f32x4 pf = *(const f32x4*)&s_pre0[er][1*52 + eub];
            f32x4 pg = *(const f32x4*)&s_pre0[er][2*52 + eub];
            f32x4 po = *(const f32x4*)&s_pre0[er][3*52 + eub];
            short hh[4], hl[4];
            #pragma unroll
            for (int e = 0; e < 4; ++e) {
                const float iv = sigf(pi[e]);
                const float fv = sigf(pf[e]);
                const float gv = tanhfast(pg[e]);
                const float ov = sigf(po[e]);
                const float c  = fv*c0r[e] + iv*gv;
                c0r[e] = c;
                const float h  = ov*tanhfast(c);
                const unsigned short hb = f2bf(h);
                hh[e] = (short)hb; hl[e] = (short)f2bf(h - bf2f(hb));
            }
            if (eub < 48) {
                *(s4v*)&s_h0hi[er][eub] = (s4v){hh[0],hh[1],hh[2],hh[3]};
                *(s4v*)&s_h0lo[er][eub] = (s4v){hl[0],hl[1],hl[2],hl[3]};
            } else {
                *(s2v*)&s_h0hi[er][eub] = (s2v){hh[0],hh[1]};
                *(s2v*)&s_h0lo[er][eub] = (s2v){hl[0],hl[1]};
            }
        }
        if (ew && n >= 1) {                            // layer-1 EW: pre1(n-1) -> h1(n-1)
            f32x4 pi = *(const f32x4*)&s_pre1[er][0*52 + eub];
            f32x4 pf = *(const f32x4*)&s_pre1[er][1*52 + eub];
            f32x4 pg = *(const f32x4*)&s_pre1[er][2*52 + eub];
            f32x4 po = *(const f32x4*)&s_pre1[er][3*52 + eub];
            short hh[4], hl[4];
            #pragma unroll
            for (int e = 0; e < 4; ++e) {
                const float iv = sigf(pi[e]);
                const float fv = sigf(pf[e]);
                const float gv = tanhfast(pg[e]);
                const float ov = sigf(po[e]);
                const float c  = fv*c1r[e] + iv*gv;
                c1r[e] = c;
                const float h  = ov*tanhfast(c);
                const unsigned short hb = f2bf(h);
                hh[e] = (short)hb; hl[e] = (short)f2bf(h - bf2f(hb));
            }
            if (eub < 48) {
                *(s4v*)&s_h1hi[er][eub] = (s4v){hh[0],hh[1],hh[2],hh[3]};
                *(s4v*)&s_h1lo[er][eub] = (s4v){hl[0],hl[1],hl[2],hl[3]};
            } else {
                *(s2v*)&s_h1hi[er][eub] = (s2v){hh[0],hh[1]};
                *(s2v*)&s_h1lo[er][eub] = (s2v){hl[0],hl[1]};
            }
        }
        if (tid >= 208 && tid < 256 && (n+1) < TT) {   // write x(n+1) into A0 k-slots
            const int p = tid - 208; const int rr = p/3, d = p%3;
            const int tn = n + 1;
            const float xv = s_xs[(tn/TC)&1][rr][(tn%TC)*3 + d];
            const unsigned short xh = f2bf(xv);
            s_h0hi[rr][HD+d] = (short)xh;
            s_h0lo[rr][HD+d] = (short)f2bf(xv - bf2f(xh));
        }
        {
            const int t2 = n + 2;                      // stage next x chunk 2 ticks ahead
            if (t2 < TT && (t2 % TC) == 0) {
                const int cb = (t2 / TC) & 1;
                for (int p = tid; p < BRR*TC*3; p += 512) {
                    const int rr = p / (TC*3), q = p % (TC*3);
                    s_xs[cb][rr][q] = x[(size_t)(r0+rr)*(TT*3) + (size_t)t2*3 + q];
                }
            }
        }
        __syncthreads();
    }

    // ---- FC epilogue: out = h1(TT-1) @ Wfc^T + bfc ----
    if (tid < BRR*7) {
        const int r = tid / 7, o = tid % 7;
        float acc = bfc[o];
        #pragma unroll
        for (int u = 0; u < HD; ++u)
            acc += (bf2f((unsigned short)s_h1hi[r][u]) + bf2f((unsigned short)s_h1lo[r][u])) * Wfc[o*HD + u];
        out[(size_t)(r0+r)*7 + o] = acc;
    }
}

extern "C" void kernel_launch(void* const* d_in, const int* in_sizes, int n_in,
                              void* d_out, int out_size, void* d_ws, size_t ws_size,
                              hipStream_t stream) {
    const float* xp    = (const float*)d_in[0];
    const float* Wih0  = (const float*)d_in[1];
    const float* Whh0  = (const float*)d_in[2];
    const float* bih0  = (const float*)d_in[3];
    const float* bhh0  = (const float*)d_in[4];
    const float* Wih1  = (const float*)d_in[5];
    const float* Whh1  = (const float*)d_in[6];
    const float* bih1  = (const float*)d_in[7];
    const float* bhh1  = (const float*)d_in[8];
    const float* Wfc   = (const float*)d_in[9];
    const float* bfc   = (const float*)d_in[10];
    float* outp = (float*)d_out;

    const int B = in_sizes[0] / (TT * 3);   // 4096
    const int grid = B / BRR;               // 256 blocks, 1 per CU

    lstm2_mfma3<<<grid, 512, 0, stream>>>(
        xp, Wih0, Whh0, bih0, bhh0, Wih1, Whh1, bih1, bhh1, Wfc, bfc, outp);
}

// Round 7
// 842.050 us; speedup vs baseline: 3.5378x; 1.0852x over previous
//
#include <hip/hip_runtime.h>
#include <math.h>

#define HD 50
#define NG 200
#define TT 512
#define BRR 16         // batch rows per block -> 256 blocks = 1/CU
#define TC 32          // x prefetch chunk (timesteps)
#define HS 72          // shorts per h row (144B stride; A-frag b128 reads conflict-free)
#define PS 212         // pre row stride: 4-row scatter delta = 16 mod 32 -> 2-way (free)

using bf16x8 = __attribute__((ext_vector_type(8))) short;
using f32x4  = __attribute__((ext_vector_type(4))) float;
using s4v    = __attribute__((ext_vector_type(4))) short;
using s2v    = __attribute__((ext_vector_type(2))) short;

__device__ __forceinline__ unsigned short f2bf(float f) {   // RNE float->bf16
    unsigned int u = __float_as_uint(f);
    u += 0x7FFFu + ((u >> 16) & 1u);
    return (unsigned short)(u >> 16);
}
__device__ __forceinline__ float bf2f(unsigned short b) {
    return __uint_as_float(((unsigned int)b) << 16);
}
__device__ __forceinline__ float frcp(float x) { return __builtin_amdgcn_rcpf(x); }
__device__ __forceinline__ float sigf(float x) { return frcp(1.0f + __expf(-x)); }
__device__ __forceinline__ float tanhfast(float x) {
    return 1.0f - 2.0f * frcp(__expf(2.0f * x) + 1.0f);
}

// Phase-parallel schedule:
//  phase1: waves 0-3 MFMA pre0(n)   || waves 4-7 EW1: pre1(n-2)->h1(n-2)
//  phase2: waves 4-7 MFMA pre1(n-1) || waves 0-3 EW0: pre0(n)->h0(n) + x-duty
// MFMA and VALU/trans pipes overlap across the two wave groups on each SIMD.
// h0 double-buffered (EW0 writes buf[n&1] while MFMA_L1 reads buf[(n-1)&1]).
__global__ __launch_bounds__(512, 2) void lstm2_mfma4(
    const float* __restrict__ x,
    const float* __restrict__ Wih0, const float* __restrict__ Whh0,
    const float* __restrict__ bih0, const float* __restrict__ bhh0,
    const float* __restrict__ Wih1, const float* __restrict__ Whh1,
    const float* __restrict__ bih1, const float* __restrict__ bhh1,
    const float* __restrict__ Wfc, const float* __restrict__ bfc,
    float* __restrict__ out)
{
    __shared__ float s_pre0[BRR][PS];                      // [row][type*52+u]
    __shared__ float s_pre1[BRR][PS];
    __shared__ short s_h0hi[2][BRR][HS], s_h0lo[2][BRR][HS]; // k: 0-49 h, 50-52 x, 53+ zero
    __shared__ short s_h1hi[BRR][HS],    s_h1lo[BRR][HS];
    __shared__ float s_xs[2][BRR][TC*3];

    const int tid  = threadIdx.x;
    const int wid  = tid >> 6;
    const int lane = tid & 63;
    const int lr   = lane & 15;    // M-row (A/D) or N-col (B/D)
    const int lq   = lane >> 4;    // k-octet
    const int r0   = blockIdx.x * BRR;
    const bool pathA = (wid < 4);

    // tile assignment: L0 tiles w0:0-3 w1:4-6 w2:7-9 w3:10-12; L1 w4:0-2 w5:3-5 w6:6-8 w7:9-12
    const int tbase = pathA ? ((wid == 0) ? 0 : 1 + wid*3) : (wid - 4)*3;
    const int tcnt  = pathA ? ((wid == 0) ? 4 : 3) : ((wid == 7) ? 4 : 3);

    // ---- weight B-fragments (hi/lo), register-resident ----
    bf16x8 bh[4][4], bl[4][4];
    int   gT[4]; int slT[4]; float bvT[4];
    #pragma unroll
    for (int tt = 0; tt < 4; ++tt) {
        #pragma unroll
        for (int s = 0; s < 4; ++s) { bh[tt][s] = (bf16x8)0; bl[tt][s] = (bf16x8)0; }
        const int g = (tbase + tt)*16 + lr;
        gT[tt] = g;
        const bool v = (tt < tcnt) && (g < NG);
        slT[tt] = v ? (g/HD)*52 + (g%HD) : 0;
        if (pathA) {
            bvT[tt] = v ? bih0[g] + bhh0[g] : 0.f;
            #pragma unroll
            for (int s = 0; s < 2; ++s) {
                #pragma unroll
                for (int j = 0; j < 8; ++j) {
                    const int k = s*32 + lq*8 + j;
                    float wv = 0.f;
                    if (v) {
                        if (k < HD) wv = Whh0[g*HD + k];
                        else if (k < HD+3) wv = Wih0[g*3 + (k-HD)];
                    }
                    const unsigned short hb = f2bf(wv);
                    bh[tt][s][j] = (short)hb;
                    bl[tt][s][j] = (short)f2bf(wv - bf2f(hb));
                }
            }
        } else {
            bvT[tt] = v ? bih1[g] + bhh1[g] : 0.f;
            #pragma unroll
            for (int s = 0; s < 4; ++s) {
                #pragma unroll
                for (int j = 0; j < 8; ++j) {
                    const int k = s*32 + lq*8 + j;   // 0-63: Wih1 k-space, 64-127: Whh1
                    float wv = 0.f;
                    if (v) {
                        if (k < HD) wv = Wih1[g*HD + k];
                        else if (k >= 64 && k < 64+HD) wv = Whh1[g*HD + (k-64)];
                    }
                    const unsigned short hb = f2bf(wv);
                    bh[tt][s][j] = (short)hb;
                    bl[tt][s][j] = (short)f2bf(wv - bf2f(hb));
                }
            }
        }
    }

    // ---- EW ownership: EW0 = tids 0-207 (waves 0-3), EW1 = tids 256-463 (waves 4-7) ----
    const bool ew0 = (tid < 208);
    const int  er0 = tid / 13;
    const int  eu0 = (tid % 13) * 4;
    const int  t2i = tid - 256;
    const bool ew1 = (t2i >= 0) && (t2i < 208);
    const int  er1 = (t2i >= 0) ? t2i / 13 : 0;
    const int  eu1 = (t2i >= 0) ? (t2i % 13) * 4 : 0;
    float c0r[4] = {0,0,0,0};
    float c1r[4] = {0,0,0,0};

    // ---- x duty: tids 208-255 (wave 3, idle in EW0) ----
    const bool xth = (tid >= 208) && (tid < 256);
    const int  xr  = (tid - 208) / 3, xd = (tid - 208) % 3;

    // ---- init LDS ----
    for (int p = tid; p < 2*BRR*HS; p += 512) {
        ((short*)s_h0hi)[p] = 0; ((short*)s_h0lo)[p] = 0;
    }
    for (int p = tid; p < BRR*HS; p += 512) {
        ((short*)s_h1hi)[p] = 0; ((short*)s_h1lo)[p] = 0;
    }
    for (int p = tid; p < 128; p += 512) {            // zero pre pad slots (u=50,51 per type)
        const int rr = p / 8, ii = p % 8;
        s_pre0[rr][(ii>>1)*52 + 50 + (ii&1)] = 0.f;
        s_pre1[rr][(ii>>1)*52 + 50 + (ii&1)] = 0.f;
    }
    for (int p = tid; p < BRR*TC*3; p += 512) {       // stage x chunk 0
        const int rr = p / (TC*3), q = p % (TC*3);
        s_xs[0][rr][q] = x[(size_t)(r0+rr)*(TT*3) + q];
    }
    __syncthreads();
    if (xth) {                                        // x(0) -> buf 1 (read at tick 0)
        const float xv = s_xs[0][xr][xd];
        const unsigned short xh = f2bf(xv);
        s_h0hi[1][xr][HD+xd] = (short)xh;
        s_h0lo[1][xr][HD+xd] = (short)f2bf(xv - bf2f(xh));
    }
    __syncthreads();

    // ================= main loop: 514 ticks =================
    for (int n = 0; n <= TT + 1; ++n) {
        // ---------- phase 1: MFMA_L0(n) on waves 0-3 || EW1(n-2) on waves 4-7 ----------
        if (pathA) {
            if (n < TT) {                              // pre0(n) = [h0(n-1)|x(n)] @ W0
                const char* hb0 = (const char*)&s_h0hi[(n+1)&1][0][0];
                const char* lb0 = (const char*)&s_h0lo[(n+1)&1][0][0];
                bf16x8 a0h[2], a0l[2];
                #pragma unroll
                for (int s = 0; s < 2; ++s) {
                    const int off = lr*(2*HS) + s*64 + lq*16;
                    a0h[s] = *(const bf16x8*)(hb0 + off);
                    a0l[s] = *(const bf16x8*)(lb0 + off);
                }
                f32x4 acc[4];
                #pragma unroll
                for (int tt = 0; tt < 4; ++tt) { const float b = bvT[tt]; acc[tt] = (f32x4){b,b,b,b}; }
                #pragma unroll
                for (int s = 0; s < 2; ++s) {
                    #pragma unroll
                    for (int tt = 0; tt < 4; ++tt) if (tt < tcnt)
                        acc[tt] = __builtin_amdgcn_mfma_f32_16x16x32_bf16(a0h[s], bh[tt][s], acc[tt], 0,0,0);
                    #pragma unroll
                    for (int tt = 0; tt < 4; ++tt) if (tt < tcnt)
                        acc[tt] = __builtin_amdgcn_mfma_f32_16x16x32_bf16(a0l[s], bh[tt][s], acc[tt], 0,0,0);
                    #pragma unroll
                    for (int tt = 0; tt < 4; ++tt) if (tt < tcnt)
                        acc[tt] = __builtin_amdgcn_mfma_f32_16x16x32_bf16(a0h[s], bl[tt][s], acc[tt], 0,0,0);
                }
                #pragma unroll
                for (int tt = 0; tt < 4; ++tt) if (tt < tcnt && gT[tt] < NG) {
                    #pragma unroll
                    for (int j = 0; j < 4; ++j) s_pre0[lq*4+j][slT[tt]] = acc[tt][j];
                }
            }
        } else {
            if (ew1 && n >= 2) {                       // EW1: pre1(n-2) -> h1(n-2)
                f32x4 pi = *(const f32x4*)&s_pre1[er1][0*52 + eu1];
                f32x4 pf = *(const f32x4*)&s_pre1[er1][1*52 + eu1];
                f32x4 pg = *(const f32x4*)&s_pre1[er1][2*52 + eu1];
                f32x4 po = *(const f32x4*)&s_pre1[er1][3*52 + eu1];
                short hh[4], hl[4];
                #pragma unroll
                for (int e = 0; e < 4; ++e) {
                    const float iv = sigf(pi[e]);
                    const float fv = sigf(pf[e]);
                    const float gv = tanhfast(pg[e]);
                    const float ov = sigf(po[e]);
                    const float c  = fv*c1r[e] + iv*gv;
                    c1r[e] = c;
                    const float h  = ov*tanhfast(c);
                    const unsigned short hb = f2bf(h);
                    hh[e] = (short)hb; hl[e] = (short)f2bf(h - bf2f(hb));
                }
                if (eu1 < 48) {
                    *(s4v*)&s_h1hi[er1][eu1] = (s4v){hh[0],hh[1],hh[2],hh[3]};
                    *(s4v*)&s_h1lo[er1][eu1] = (s4v){hl[0],hl[1],hl[2],hl[3]};
                } else {
                    *(s2v*)&s_h1hi[er1][eu1] = (s2v){hh[0],hh[1]};
                    *(s2v*)&s_h1lo[er1][eu1] = (s2v){hl[0],hl[1]};
                }
            }
        }
        __syncthreads();

        // ---------- phase 2: MFMA_L1(n-1) on waves 4-7 || EW0(n) + x-duty on waves 0-3 ----------
        if (!pathA) {
            if (n >= 1 && n <= TT) {                   // pre1(n-1) = [h0(n-1)|h1(n-2)] @ W1
                const char* hb0 = (const char*)&s_h0hi[(n+1)&1][0][0];
                const char* lb0 = (const char*)&s_h0lo[(n+1)&1][0][0];
                bf16x8 ah[4], al[4];
                #pragma unroll
                for (int s = 0; s < 2; ++s) {
                    const int off = lr*(2*HS) + s*64 + lq*16;
                    ah[s]   = *(const bf16x8*)(hb0 + off);
                    al[s]   = *(const bf16x8*)(lb0 + off);
                    ah[2+s] = *(const bf16x8*)((const char*)&s_h1hi[0][0] + off);
                    al[2+s] = *(const bf16x8*)((const char*)&s_h1lo[0][0] + off);
                }
                f32x4 acc[4];
                #pragma unroll
                for (int tt = 0; tt < 4; ++tt) { const float b = bvT[tt]; acc[tt] = (f32x4){b,b,b,b}; }
                #pragma unroll
                for (int s = 0; s < 4; ++s) {
                    #pragma unroll
                    for (int tt = 0; tt < 4; ++tt) if (tt < tcnt)
                        acc[tt] = __builtin_amdgcn_mfma_f32_16x16x32_bf16(ah[s], bh[tt][s], acc[tt], 0,0,0);
                    #pragma unroll
                    for (int tt = 0; tt < 4; ++tt) if (tt < tcnt)
                        acc[tt] = __builtin_amdgcn_mfma_f32_16x16x32_bf16(al[s], bh[tt][s], acc[tt], 0,0,0);
                    #pragma unroll
                    for (int tt = 0; tt < 4; ++tt) if (tt < tcnt)
                        acc[tt] = __builtin_amdgcn_mfma_f32_16x16x32_bf16(ah[s], bl[tt][s], acc[tt], 0,0,0);
                }
                #pragma unroll
                for (int tt = 0; tt < 4; ++tt) if (tt < tcnt && gT[tt] < NG) {
                    #pragma unroll
                    for (int j = 0; j < 4; ++j) s_pre1[lq*4+j][slT[tt]] = acc[tt][j];
                }
            }
        } else {
            if (ew0 && n < TT) {                       // EW0: pre0(n) -> h0(n) in buf[n&1]
                f32x4 pi = *(const f32x4*)&s_pre0[er0][0*52 + eu0];
                f32x4 pf = *(const f32x4*)&s_pre0[er0][1*52 + eu0];
                f32x4 pg = *(const f32x4*)&s_pre0[er0][2*52 + eu0];
                f32x4 po = *(const f32x4*)&s_pre0[er0][3*52 + eu0];
                short hh[4], hl[4];
                #pragma unroll
                for (int e = 0; e < 4; ++e) {
                    const float iv = sigf(pi[e]);
                    const float fv = sigf(pf[e]);
                    const float gv = tanhfast(pg[e]);
                    const float ov = sigf(po[e]);
                    const float c  = fv*c0r[e] + iv*gv;
                    c0r[e] = c;
                    const float h  = ov*tanhfast(c);
                    const unsigned short hb = f2bf(h);
                    hh[e] = (short)hb; hl[e] = (short)f2bf(h - bf2f(hb));
                }
                if (eu0 < 48) {
                    *(s4v*)&s_h0hi[n&1][er0][eu0] = (s4v){hh[0],hh[1],hh[2],hh[3]};
                    *(s4v*)&s_h0lo[n&1][er0][eu0] = (s4v){hl[0],hl[1],hl[2],hl[3]};
                } else {
                    *(s2v*)&s_h0hi[n&1][er0][eu0] = (s2v){hh[0],hh[1]};
                    *(s2v*)&s_h0lo[n&1][er0][eu0] = (s2v){hl[0],hl[1]};
                }
            }
            if (xth && (n+1) < TT) {                   // x(n+1) -> buf[n&1] k-slots 50-52
                const int tn = n + 1;
                const float xv = s_xs[(tn/TC)&1][xr][(tn%TC)*3 + xd];
                const unsigned short xh = f2bf(xv);
                s_h0hi[n&1][xr][HD+xd] = (short)xh;
                s_h0lo[n&1][xr][HD+xd] = (short)f2bf(xv - bf2f(xh));
            }
        }
        {
            const int t2s = n + 2;                     // stage next x chunk 2 ticks ahead
            if (t2s < TT && (t2s % TC) == 0) {
                const int cb = (t2s / TC) & 1;
                for (int p = tid; p < BRR*TC*3; p += 512) {
                    const int rr = p / (TC*3), q = p % (TC*3);
                    s_xs[cb][rr][q] = x[(size_t)(r0+rr)*(TT*3) + (size_t)t2s*3 + q];
                }
            }
        }
        __syncthreads();
    }

    // ---- FC epilogue: out = h1(TT-1) @ Wfc^T + bfc ----
    if (tid < BRR*7) {
        const int r = tid / 7, o = tid % 7;
        float acc = bfc[o];
        #pragma unroll
        for (int u = 0; u < HD; ++u)
            acc += (bf2f((unsigned short)s_h1hi[r][u]) + bf2f((unsigned short)s_h1lo[r][u])) * Wfc[o*HD + u];
        out[(size_t)(r0+r)*7 + o] = acc;
    }
}

extern "C" void kernel_launch(void* const* d_in, const int* in_sizes, int n_in,
                              void* d_out, int out_size, void* d_ws, size_t ws_size,
                              hipStream_t stream) {
    const float* xp    = (const float*)d_in[0];
    const float* Wih0  = (const float*)d_in[1];
    const float* Whh0  = (const float*)d_in[2];
    const float* bih0  = (const float*)d_in[3];
    const float* bhh0  = (const float*)d_in[4];
    const float* Wih1  = (const float*)d_in[5];
    const float* Whh1  = (const float*)d_in[6];
    const float* bih1  = (const float*)d_in[7];
    const float* bhh1  = (const float*)d_in[8];
    const float* Wfc   = (const float*)d_in[9];
    const float* bfc   = (const float*)d_in[10];
    float* outp = (float*)d_out;

    const int B = in_sizes[0] / (TT * 3);   // 4096
    const int grid = B / BRR;               // 256 blocks, 1 per CU

    lstm2_mfma4<<<grid, 512, 0, stream>>>(
        xp, Wih0, Whh0, bih0, bhh0, Wih1, Whh1, bih1, bhh1, Wfc, bfc, outp);
}

// Round 8
// 615.175 us; speedup vs baseline: 4.8425x; 1.3688x over previous
//
#include <hip/hip_runtime.h>

#define HD 50
#define TT 512
#define BRR 16        // batch rows per block -> 256 blocks = 1/CU
#define TC 32         // x prefetch chunk (timesteps)
#define HS 72         // shorts per h row (144B stride; b128 A-reads conflict-free)

using bf16x8 = __attribute__((ext_vector_type(8))) short;
using f32x4  = __attribute__((ext_vector_type(4))) float;

__device__ __forceinline__ unsigned short f2bf(float f) {   // RNE float->bf16
    unsigned int u = __float_as_uint(f);
    u += 0x7FFFu + ((u >> 16) & 1u);
    return (unsigned short)(u >> 16);
}
__device__ __forceinline__ float bf2f(unsigned short b) {
    return __uint_as_float(((unsigned int)b) << 16);
}
__device__ __forceinline__ float frcp(float x) { return __builtin_amdgcn_rcpf(x); }
__device__ __forceinline__ float sigf(float x) { return frcp(1.0f + __expf(-x)); }
__device__ __forceinline__ float tanhfast(float x) {
    return 1.0f - 2.0f * frcp(__expf(2.0f * x) + 1.0f);
}

// Gate-major tile mapping: wave (wid&3)=w owns units u = 4*lr + w (u<50); its 4
// tiles are the 4 gate types of those units. After MFMA, lane (lr,lq) holds
// acc[gate][j] for unit u, rows 4*lq+j -> EW fully in-register, no s_pre, no
// gate scatter, ONE barrier per tick. h0 and h1 double-buffered.
// Waves 0-3: layer 0 (step n). Waves 4-7: layer 1 (step n-1).
__global__ __launch_bounds__(512, 2) void lstm2_mfma5(
    const float* __restrict__ x,
    const float* __restrict__ Wih0, const float* __restrict__ Whh0,
    const float* __restrict__ bih0, const float* __restrict__ bhh0,
    const float* __restrict__ Wih1, const float* __restrict__ Whh1,
    const float* __restrict__ bih1, const float* __restrict__ bhh1,
    const float* __restrict__ Wfc, const float* __restrict__ bfc,
    float* __restrict__ out)
{
    __shared__ short s_h0hi[2][BRR][HS], s_h0lo[2][BRR][HS]; // k: 0-49 h0, 50-52 x, 53+ 0
    __shared__ short s_h1hi[2][BRR][HS], s_h1lo[2][BRR][HS]; // k: 0-49 h1, 50+ 0
    __shared__ float s_xs[2][BRR][TC*3];

    const int tid  = threadIdx.x;
    const int wid  = tid >> 6;
    const int lane = tid & 63;
    const int lr   = lane & 15;    // B/D column = unit slot
    const int lq   = lane >> 4;    // k-octet / D row-quad
    const int r0   = blockIdx.x * BRR;
    const bool pathA = (wid < 4);
    const int  wsub  = wid & 3;
    const int  u     = lr * 4 + wsub;      // this lane's hidden unit
    const bool valid = (u < HD);

    // ---- weight B-fragments (hi/lo), register-resident; tile tt = gate type ----
    bf16x8 bh[4][4], bl[4][4];
    float bvT[4];
    #pragma unroll
    for (int tt = 0; tt < 4; ++tt) {
        #pragma unroll
        for (int s = 0; s < 4; ++s) { bh[tt][s] = (bf16x8)0; bl[tt][s] = (bf16x8)0; }
        const int g = tt * HD + (valid ? u : 0);     // gate-row in [0,200)
        if (pathA) {
            bvT[tt] = valid ? bih0[g] + bhh0[g] : 0.f;
            #pragma unroll
            for (int s = 0; s < 2; ++s) {
                #pragma unroll
                for (int j = 0; j < 8; ++j) {
                    const int k = s*32 + lq*8 + j;
                    float wv = 0.f;
                    if (valid) {
                        if (k < HD) wv = Whh0[g*HD + k];
                        else if (k < HD+3) wv = Wih0[g*3 + (k-HD)];
                    }
                    const unsigned short hb = f2bf(wv);
                    bh[tt][s][j] = (short)hb;
                    bl[tt][s][j] = (short)f2bf(wv - bf2f(hb));
                }
            }
        } else {
            bvT[tt] = valid ? bih1[g] + bhh1[g] : 0.f;
            #pragma unroll
            for (int s = 0; s < 4; ++s) {
                #pragma unroll
                for (int j = 0; j < 8; ++j) {
                    const int k = s*32 + lq*8 + j;   // 0-63: Wih1 k-space, 64-127: Whh1
                    float wv = 0.f;
                    if (valid) {
                        if (k < HD) wv = Wih1[g*HD + k];
                        else if (k >= 64 && k < 64+HD) wv = Whh1[g*HD + (k-64)];
                    }
                    const unsigned short hb = f2bf(wv);
                    bh[tt][s][j] = (short)hb;
                    bl[tt][s][j] = (short)f2bf(wv - bf2f(hb));
                }
            }
        }
    }

    // ---- per-lane c-state: 4 batch rows (4*lq+j) of unit u ----
    float cst[4] = {0.f, 0.f, 0.f, 0.f};

    // ---- x duty: tids 0-47 (subset of wave 0) ----
    const bool xth = (tid < 48);
    const int  xr  = tid / 3, xd = tid % 3;

    // ---- init LDS ----
    for (int p = tid; p < 2*BRR*HS; p += 512) {
        ((short*)s_h0hi)[p] = 0; ((short*)s_h0lo)[p] = 0;
        ((short*)s_h1hi)[p] = 0; ((short*)s_h1lo)[p] = 0;
    }
    for (int p = tid; p < BRR*TC*3; p += 512) {       // stage x chunk 0
        const int rr = p / (TC*3), q = p % (TC*3);
        s_xs[0][rr][q] = x[(size_t)(r0+rr)*(TT*3) + q];
    }
    __syncthreads();
    if (xth) {                                        // x(0) -> h0 buf 1 (read at tick 0)
        const float xv = s_xs[0][xr][xd];
        const unsigned short xh = f2bf(xv);
        s_h0hi[1][xr][HD+xd] = (short)xh;
        s_h0lo[1][xr][HD+xd] = (short)f2bf(xv - bf2f(xh));
    }
    __syncthreads();

    // ================= main loop: TT+1 ticks, ONE barrier each =================
    for (int n = 0; n <= TT; ++n) {
        if (pathA) {
            if (n < TT) {                              // pre0(n) = [h0(n-1)|x(n)] @ W0
                const char* hb0 = (const char*)&s_h0hi[(n+1)&1][0][0];
                const char* lb0 = (const char*)&s_h0lo[(n+1)&1][0][0];
                bf16x8 ah[2], al[2];
                #pragma unroll
                for (int s = 0; s < 2; ++s) {
                    const int off = lr*(2*HS) + s*64 + lq*16;
                    ah[s] = *(const bf16x8*)(hb0 + off);
                    al[s] = *(const bf16x8*)(lb0 + off);
                }
                f32x4 acc[4];
                #pragma unroll
                for (int tt = 0; tt < 4; ++tt) { const float b = bvT[tt]; acc[tt] = (f32x4){b,b,b,b}; }
                #pragma unroll
                for (int s = 0; s < 2; ++s) {
                    #pragma unroll
                    for (int tt = 0; tt < 4; ++tt)
                        acc[tt] = __builtin_amdgcn_mfma_f32_16x16x32_bf16(ah[s], bh[tt][s], acc[tt], 0,0,0);
                    #pragma unroll
                    for (int tt = 0; tt < 4; ++tt)
                        acc[tt] = __builtin_amdgcn_mfma_f32_16x16x32_bf16(al[s], bh[tt][s], acc[tt], 0,0,0);
                    #pragma unroll
                    for (int tt = 0; tt < 4; ++tt)
                        acc[tt] = __builtin_amdgcn_mfma_f32_16x16x32_bf16(ah[s], bl[tt][s], acc[tt], 0,0,0);
                }
                if (valid) {                           // EW0 in-register -> h0(n) in buf[n&1]
                    #pragma unroll
                    for (int j = 0; j < 4; ++j) {
                        const float iv = sigf(acc[0][j]);
                        const float fv = sigf(acc[1][j]);
                        const float gv = tanhfast(acc[2][j]);
                        const float ov = sigf(acc[3][j]);
                        const float c  = fv*cst[j] + iv*gv;
                        cst[j] = c;
                        const float h  = ov*tanhfast(c);
                        const unsigned short hb2 = f2bf(h);
                        s_h0hi[n&1][lq*4+j][u] = (short)hb2;
                        s_h0lo[n&1][lq*4+j][u] = (short)f2bf(h - bf2f(hb2));
                    }
                }
            }
            if (xth && (n+1) < TT) {                   // x(n+1) -> h0 buf[n&1] k-slots 50-52
                const int tn = n + 1;
                const float xv = s_xs[(tn/TC)&1][xr][(tn%TC)*3 + xd];
                const unsigned short xh = f2bf(xv);
                s_h0hi[n&1][xr][HD+xd] = (short)xh;
                s_h0lo[n&1][xr][HD+xd] = (short)f2bf(xv - bf2f(xh));
            }
        } else {
            if (n >= 1) {                              // pre1(n-1) = [h0(n-1)|h1(n-2)] @ W1
                const char* hb0 = (const char*)&s_h0hi[(n+1)&1][0][0];
                const char* lb0 = (const char*)&s_h0lo[(n+1)&1][0][0];
                const char* hb1 = (const char*)&s_h1hi[n&1][0][0];
                const char* lb1 = (const char*)&s_h1lo[n&1][0][0];
                bf16x8 ah[4], al[4];
                #pragma unroll
                for (int s = 0; s < 2; ++s) {
                    const int off = lr*(2*HS) + s*64 + lq*16;
                    ah[s]   = *(const bf16x8*)(hb0 + off);
                    al[s]   = *(const bf16x8*)(lb0 + off);
                    ah[2+s] = *(const bf16x8*)(hb1 + off);
                    al[2+s] = *(const bf16x8*)(lb1 + off);
                }
                f32x4 acc[4];
                #pragma unroll
                for (int tt = 0; tt < 4; ++tt) { const float b = bvT[tt]; acc[tt] = (f32x4){b,b,b,b}; }
                #pragma unroll
                for (int s = 0; s < 4; ++s) {
                    #pragma unroll
                    for (int tt = 0; tt < 4; ++tt)
                        acc[tt] = __builtin_amdgcn_mfma_f32_16x16x32_bf16(ah[s], bh[tt][s], acc[tt], 0,0,0);
                    #pragma unroll
                    for (int tt = 0; tt < 4; ++tt)
                        acc[tt] = __builtin_amdgcn_mfma_f32_16x16x32_bf16(al[s], bh[tt][s], acc[tt], 0,0,0);
                    #pragma unroll
                    for (int tt = 0; tt < 4; ++tt)
                        acc[tt] = __builtin_amdgcn_mfma_f32_16x16x32_bf16(ah[s], bl[tt][s], acc[tt], 0,0,0);
                }
                if (valid) {                           // EW1 in-register -> h1(n-1) in buf[(n+1)&1]
                    #pragma unroll
                    for (int j = 0; j < 4; ++j) {
                        const float iv = sigf(acc[0][j]);
                        const float fv = sigf(acc[1][j]);
                        const float gv = tanhfast(acc[2][j]);
                        const float ov = sigf(acc[3][j]);
                        const float c  = fv*cst[j] + iv*gv;
                        cst[j] = c;
                        const float h  = ov*tanhfast(c);
                        const unsigned short hb2 = f2bf(h);
                        s_h1hi[(n+1)&1][lq*4+j][u] = (short)hb2;
                        s_h1lo[(n+1)&1][lq*4+j][u] = (short)f2bf(h - bf2f(hb2));
                    }
                }
            }
        }
        {
            const int t2s = n + 2;                     // stage next x chunk 2 ticks ahead
            if (t2s < TT && (t2s % TC) == 0) {
                const int cb = (t2s / TC) & 1;
                for (int p = tid; p < BRR*TC*3; p += 512) {
                    const int rr = p / (TC*3), q = p % (TC*3);
                    s_xs[cb][rr][q] = x[(size_t)(r0+rr)*(TT*3) + (size_t)t2s*3 + q];
                }
            }
        }
        __syncthreads();
    }

    // ---- FC epilogue: out = h1(TT-1) @ Wfc^T + bfc  (h1(511) in buf 1) ----
    if (tid < BRR*7) {
        const int r = tid / 7, o = tid % 7;
        float acc = bfc[o];
        #pragma unroll
        for (int uu = 0; uu < HD; ++uu)
            acc += (bf2f((unsigned short)s_h1hi[1][r][uu]) + bf2f((unsigned short)s_h1lo[1][r][uu])) * Wfc[o*HD + uu];
        out[(size_t)(r0+r)*7 + o] = acc;
    }
}

extern "C" void kernel_launch(void* const* d_in, const int* in_sizes, int n_in,
                              void* d_out, int out_size, void* d_ws, size_t ws_size,
                              hipStream_t stream) {
    const float* xp    = (const float*)d_in[0];
    const float* Wih0  = (const float*)d_in[1];
    const float* Whh0  = (const float*)d_in[2];
    const float* bih0  = (const float*)d_in[3];
    const float* bhh0  = (const float*)d_in[4];
    const float* Wih1  = (const float*)d_in[5];
    const float* Whh1  = (const float*)d_in[6];
    const float* bih1  = (const float*)d_in[7];
    const float* bhh1  = (const float*)d_in[8];
    const float* Wfc   = (const float*)d_in[9];
    const float* bfc   = (const float*)d_in[10];
    float* outp = (float*)d_out;

    const int B = in_sizes[0] / (TT * 3);   // 4096
    const int grid = B / BRR;               // 256 blocks, 1 per CU

    lstm2_mfma5<<<grid, 512, 0, stream>>>(
        xp, Wih0, Whh0, bih0, bhh0, Wih1, Whh1, bih1, bhh1, Wfc, bfc, outp);
}